// Round 4
// baseline (475.805 us; speedup 1.0000x reference)
//
#include <hip/hip_runtime.h>
#include <hip/hip_bf16.h>
#include <stdint.h>

#define D_MODEL 1024
#define NHEADS  16
#define DH      64
#define NBATCH  4
#define SEQLEN  4096
#define MROWS   (NBATCH*SEQLEN)   // 16384
#define EPSV    1e-10f

typedef __hip_bfloat16 bf16;
typedef unsigned short ushort_t;
typedef __attribute__((ext_vector_type(8))) short short8;   // 8 bf16 (4 VGPRs)
typedef __attribute__((ext_vector_type(4))) float f32x4;

struct __align__(8) bf16x4s { bf16 a, b, c, d; };

__device__ __forceinline__ void async_copy16(void* lds, const void* g) {
  __builtin_amdgcn_global_load_lds(
      (const __attribute__((address_space(1))) unsigned int*)(uintptr_t)g,
      (__attribute__((address_space(3))) unsigned int*)(uintptr_t)lds,
      16, 0, 0);
}

// ---------------- f32 -> bf16 conversion (vectorized, exact grid) ----------------
__global__ __launch_bounds__(256)
void cvt_bf16(const float* __restrict__ s, bf16* __restrict__ d) {
  const int i = blockIdx.x * 256 + threadIdx.x;
  const f32x4 v = ((const f32x4*)s)[i];
  bf16x4s o;
  o.a = __float2bfloat16(v[0]);
  o.b = __float2bfloat16(v[1]);
  o.c = __float2bfloat16(v[2]);
  o.d = __float2bfloat16(v[3]);
  ((bf16x4s*)d)[i] = o;
}

// ---------------- weight transpose + cvt (W[K,N] f32 -> WT[N,K] bf16) ----------------
__global__ void transpose4(const float* __restrict__ s0, const float* __restrict__ s1,
                           const float* __restrict__ s2, const float* __restrict__ s3,
                           bf16* __restrict__ d0, bf16* __restrict__ d1,
                           bf16* __restrict__ d2, bf16* __restrict__ d3) {
  const float* s; bf16* d;
  switch (blockIdx.z) {
    case 0: s = s0; d = d0; break;
    case 1: s = s1; d = d1; break;
    case 2: s = s2; d = d2; break;
    default: s = s3; d = d3; break;
  }
  __shared__ float tile[32][33];
  int x = blockIdx.x*32 + threadIdx.x;
  int y = blockIdx.y*32 + threadIdx.y;
  tile[threadIdx.y][threadIdx.x] = s[(size_t)y*D_MODEL + x];
  __syncthreads();
  int xo = blockIdx.y*32 + threadIdx.x;
  int yo = blockIdx.x*32 + threadIdx.y;
  d[(size_t)yo*D_MODEL + xo] = __float2bfloat16(tile[threadIdx.x][threadIdx.y]);
}

// ---------------- GEMM: C = act(A[M,K] @ BT[N,K]^T + bias) ----------------
// Round-2 proven config: 128x256 tile, BK=32, 8 waves (2Mx4N, 64x64 each),
// double-buffered LDS, counted-vmcnt 2-phase schedule (T3/T4), XCD swizzle.
// TRANS=1: write output transposed as C_T[N][M] (r2 contiguous -> 8B stores).
__device__ __forceinline__ void storeC(float* p, float v) { *p = v; }
__device__ __forceinline__ void storeC(bf16*  p, float v) { *p = __float2bfloat16(v); }

template<int ACT, int TRANS, typename CT>
__global__ __launch_bounds__(512, 4)
void gemm_bias_act(const bf16* __restrict__ A, const bf16* __restrict__ BT,
                   const float* __restrict__ bias, CT* __restrict__ C,
                   int M, int N, int K) {
  __shared__ __align__(16) short Asm[2][128*32];
  __shared__ __align__(16) short Bsm[2][256*32];
  const int tid  = threadIdx.x;          // 0..511
  const int wave = tid >> 6;             // 0..7
  const int lane = tid & 63;

  // XCD-aware bijective swizzle of the flattened block id (nwg % 8 == 0)
  const int nbx = N >> 8;                            // N/256
  const int nwg = (M >> 7) * nbx;
  int fid = blockIdx.y * nbx + blockIdx.x;
  fid = (fid & 7) * (nwg >> 3) + (fid >> 3);
  const int m0 = (fid / nbx) * 128;
  const int n0 = (fid % nbx) * 256;

  const int wr = wave >> 2, wc = wave & 3;           // 2M x 4N wave grid
  const int srow = tid >> 2;                         // 0..127 staging row
  const int ldst = (tid & 3) * 8;                    // linear LDS slot (shorts)
  const int sgrp = ((tid & 3) ^ ((srow >> 1) & 3)) * 8;  // swizzled source col-group
  const int fr   = lane & 15;
  const int quad = lane >> 4;
  const int sslot = (quad ^ ((fr >> 1) & 3)) * 8;    // swizzled read slot

  f32x4 acc[4][4] = {};
  const int nk = K / 32;

  // prologue: stage tile 0 into buffer 0 (3 loads/thread: 1 A-row, 2 B-rows)
  async_copy16(&Asm[0][srow*32 + ldst], A + (size_t)(m0+srow)*K + sgrp);
  #pragma unroll
  for (int r = 0; r < 2; ++r) {
    const int row = r*128 + srow;
    async_copy16(&Bsm[0][row*32 + ldst], BT + (size_t)(n0+row)*K + sgrp);
  }

  int cur = 0;
  for (int t = 0; t < nk; ++t) {
    if (t + 1 < nk) {
      const int k0n = (t + 1) * 32;
      async_copy16(&Asm[cur^1][srow*32 + ldst], A + (size_t)(m0+srow)*K + k0n + sgrp);
      #pragma unroll
      for (int r = 0; r < 2; ++r) {
        const int row = r*128 + srow;
        async_copy16(&Bsm[cur^1][row*32 + ldst], BT + (size_t)(n0+row)*K + k0n + sgrp);
      }
      asm volatile("s_waitcnt vmcnt(3)" ::: "memory");  // tile t's 3 loads done
    } else {
      asm volatile("s_waitcnt vmcnt(0)" ::: "memory");  // last tile: full drain
    }
    asm volatile("s_barrier" ::: "memory");             // buf[cur] ready for all

    short8 afr[4], bfr[4];
    #pragma unroll
    for (int i = 0; i < 4; ++i)
      afr[i] = *(const short8*)&Asm[cur][(wr*64 + i*16 + fr)*32 + sslot];
    #pragma unroll
    for (int j = 0; j < 4; ++j)
      bfr[j] = *(const short8*)&Bsm[cur][(wc*64 + j*16 + fr)*32 + sslot];

    __builtin_amdgcn_s_setprio(1);
    #pragma unroll
    for (int i = 0; i < 4; ++i)
      #pragma unroll
      for (int j = 0; j < 4; ++j)
        acc[i][j] = __builtin_amdgcn_mfma_f32_16x16x32_bf16(afr[i], bfr[j], acc[i][j], 0, 0, 0);
    __builtin_amdgcn_s_setprio(0);

    asm volatile("s_barrier" ::: "memory");             // reads done before overwrite
    cur ^= 1;
  }

  // C/D layout: col(n)=lane&15, row(m)=quad*4+reg  [measured m89/m91]
  #pragma unroll
  for (int j = 0; j < 4; ++j) {
    const int gn = n0 + wc*64 + j*16 + fr;
    const float bv = bias[gn];
    #pragma unroll
    for (int i = 0; i < 4; ++i) {
      const int gm = m0 + wr*64 + i*16 + quad*4;
      if (TRANS) {
        float vv[4];
        #pragma unroll
        for (int r2 = 0; r2 < 4; ++r2) {
          float v = acc[i][j][r2] + bv;
          if (ACT) v = (v > 0.f) ? (v + 1.f) : __expf(v);
          vv[r2] = v;
        }
        bf16x4s o{__float2bfloat16(vv[0]), __float2bfloat16(vv[1]),
                  __float2bfloat16(vv[2]), __float2bfloat16(vv[3])};
        *(bf16x4s*)((bf16*)C + (size_t)gn*M + gm) = o;   // C_T[N][M], r2 contiguous
      } else {
        #pragma unroll
        for (int r2 = 0; r2 < 4; ++r2) {
          float v = acc[i][j][r2] + bv;
          if (ACT) v = (v > 0.f) ? (v + 1.f) : __expf(v);   // elu(x)+1
          storeC(&C[(size_t)(gm + r2)*N + gn], v);
        }
      }
    }
  }
}

// ---------------- KV + K_sum partials via MFMA (transposed inputs) ----------------
// KT,VT are [1024][MROWS] bf16 (pre-transposed by the K/V projection GEMMs).
// Per block (nh, sp): KV[m][d] += sum_{s in strip} VT[h*64+m][s] * KT[h*64+d][s].
// Fragments load DIRECTLY global->VGPR (s-contiguous 16B). No LDS, no barriers.
// Ksum via ones-row MFMA: C[m][d] = sum_s 1.0*K[d][s] (wave 0 only).
#define KV_SPLIT 16
__global__ __launch_bounds__(256)
void kv_kernel(const bf16* __restrict__ KT, const bf16* __restrict__ VT,
               float* __restrict__ KVp, float* __restrict__ Ksp) {
  const int b  = blockIdx.x;
  const int sp = b & (KV_SPLIT-1);
  const int nh = b >> 4;
  const int h = nh & (NHEADS-1), n = nh >> 4;
  const int tid = threadIdx.x;
  const int w = tid >> 6, lane = tid & 63;
  const int fr = lane & 15, quad = lane >> 4;

  const size_t cbase = (size_t)n*SEQLEN + sp*(SEQLEN/KV_SPLIT);
  const bf16* KTh = KT + (size_t)(h*DH)*MROWS + cbase;
  const bf16* VTh = VT + (size_t)(h*DH)*MROWS + cbase;

  f32x4 acc[4] = {};
  f32x4 ksacc[4] = {};
  const short8 ones8 = {0x3F80,0x3F80,0x3F80,0x3F80,0x3F80,0x3F80,0x3F80,0x3F80};

  #pragma unroll
  for (int ks = 0; ks < 8; ++ks) {        // 8 x 32 = 256 s per block
    const int sc = ks*32 + quad*8;
    const short8 av = *(const short8*)(VTh + (size_t)(w*16 + fr)*MROWS + sc);
    #pragma unroll
    for (int j = 0; j < 4; ++j) {
      const short8 bk = *(const short8*)(KTh + (size_t)(j*16 + fr)*MROWS + sc);
      acc[j] = __builtin_amdgcn_mfma_f32_16x16x32_bf16(av, bk, acc[j], 0, 0, 0);
      if (w == 0)
        ksacc[j] = __builtin_amdgcn_mfma_f32_16x16x32_bf16(ones8, bk, ksacc[j], 0, 0, 0);
    }
  }

  // KV partial: m = w*16 + quad*4 + r, col d = j*16 + fr
  float* outp = KVp + (size_t)b*4096;
  #pragma unroll
  for (int j = 0; j < 4; ++j)
    #pragma unroll
    for (int r = 0; r < 4; ++r)
      outp[(w*16 + quad*4 + r)*64 + j*16 + fr] = acc[j][r];

  if (tid < 16)   // wave 0, quad 0: every C-row of ones-MFMA equals Ksum_partial
    #pragma unroll
    for (int j = 0; j < 4; ++j)
      Ksp[b*64 + j*16 + tid] = ksacc[j][0];
}

// ---------------- reduce 16 partials -> KVb (bf16 hi/lo, vlin B-frag layout) ----
// KVb[nh][144][64]: rows 0-63 hi(KV[m][d]), 64-127 lo, 128/129 Ksum hi/lo,
// 130-143 zero pad (so vlin's j=8 fragment rows are defined).
__global__ __launch_bounds__(256)
void kv_reduce(const float* __restrict__ KVp, const float* __restrict__ Ksp,
               bf16* __restrict__ KVb) {
  const int c  = blockIdx.x;    // 0..3
  const int nh = blockIdx.y;    // 0..63
  const int tid = threadIdx.x;
  const int e = c*1024 + tid*4;
  const int m = e >> 6, d = e & 63;
  f32x4 s = {};
  #pragma unroll
  for (int sp = 0; sp < KV_SPLIT; ++sp)
    s += *(const f32x4*)(KVp + ((size_t)(nh*KV_SPLIT + sp))*4096 + e);

  bf16* base = KVb + (size_t)nh*(144*64);
  bf16 h0 = __float2bfloat16(s[0]), h1 = __float2bfloat16(s[1]);
  bf16 h2 = __float2bfloat16(s[2]), h3 = __float2bfloat16(s[3]);
  bf16x4s hi4{h0, h1, h2, h3};
  bf16x4s lo4{__float2bfloat16(s[0] - __bfloat162float(h0)),
              __float2bfloat16(s[1] - __bfloat162float(h1)),
              __float2bfloat16(s[2] - __bfloat162float(h2)),
              __float2bfloat16(s[3] - __bfloat162float(h3))};
  *(bf16x4s*)&base[m*64 + d]        = hi4;
  *(bf16x4s*)&base[(64 + m)*64 + d] = lo4;

  if (c == 0) {
    if (tid < 64) {
      float ks = 0.f;
      #pragma unroll
      for (int sp = 0; sp < KV_SPLIT; ++sp)
        ks += Ksp[(nh*KV_SPLIT + sp)*64 + tid];
      bf16 hh = __float2bfloat16(ks);
      base[128*64 + tid] = hh;
      base[129*64 + tid] = __float2bfloat16(ks - __bfloat162float(hh));
    }
    for (int i2 = tid; i2 < 14*64; i2 += 256)
      base[130*64 + i2] = __float2bfloat16(0.0f);
  }
}

// ---------------- V_lin = Z * (Q_lin . KV) — direct-register MFMA, no LDS ----
__global__ __launch_bounds__(256)
void vlin_kernel(const bf16* __restrict__ Ql, const bf16* __restrict__ KVb,
                 bf16* __restrict__ Vl) {
  const int lc = blockIdx.x;            // l-chunk of 128 rows (32 total)
  const int nh = blockIdx.y;            // n*NHEADS + h
  const int h = nh & (NHEADS-1), n = nh >> 4;
  const int tid = threadIdx.x, wave = tid >> 6, lane = tid & 63;
  const int fr = lane & 15, quad = lane >> 4;

  // ---- A fragments: direct global -> VGPR ----
  const int l0 = lc * 128;
  const size_t qbase = ((size_t)(n*SEQLEN) + l0)*D_MODEL + h*DH;
  short8 afr[2][2];
  #pragma unroll
  for (int i = 0; i < 2; ++i)
    #pragma unroll
    for (int ks = 0; ks < 2; ++ks)
      afr[i][ks] = *(const short8*)(Ql + qbase +
                     (size_t)(wave*32 + i*16 + fr)*D_MODEL + ks*32 + quad*8);

  // ---- B fragments: direct from KVb (L2-resident, frag-ready layout) ----
  const bf16* bb = KVb + (size_t)nh*(144*64);
  f32x4 acc[2][9] = {};
  #pragma unroll
  for (int ks = 0; ks < 2; ++ks) {
    #pragma unroll
    for (int j = 0; j < 9; ++j) {
      const short8 bfr = *(const short8*)(bb + (j*16 + fr)*64 + ks*32 + quad*8);
      #pragma unroll
      for (int i = 0; i < 2; ++i)
        acc[i][j] = __builtin_amdgcn_mfma_f32_16x16x32_bf16(afr[i][ks], bfr, acc[i][j], 0, 0, 0);
    }
  }

  // ---- scale + store; Z via shfl broadcast (no LDS, no barriers) ----
  #pragma unroll
  for (int i = 0; i < 2; ++i) {
    #pragma unroll
    for (int r2 = 0; r2 < 4; ++r2) {
      const float v = acc[i][8][r2];
      const float vp = v + __shfl_xor(v, 1, 64);          // P128 + P129 (valid at fr=0)
      const float z = 1.0f / (__shfl(vp, lane & 48, 64) + EPSV);  // bcast from quad's fr=0
      const int rloc = wave*32 + i*16 + quad*4 + r2;
      #pragma unroll
      for (int j = 0; j < 4; ++j) {
        const float num = acc[i][j][r2] + acc[i][4 + j][r2];
        Vl[qbase + (size_t)rloc*D_MODEL + j*16 + fr] = __float2bfloat16(num * z);
      }
    }
  }
}

// ---------------- launch ----------------
extern "C" void kernel_launch(void* const* d_in, const int* in_sizes, int n_in,
                              void* d_out, int out_size, void* d_ws, size_t ws_size,
                              hipStream_t stream) {
  const float* q  = (const float*)d_in[0];
  const float* k  = (const float*)d_in[1];
  const float* v  = (const float*)d_in[2];
  const float* Wq = (const float*)d_in[3];
  const float* bq = (const float*)d_in[4];
  const float* Wk = (const float*)d_in[5];
  const float* bk = (const float*)d_in[6];
  const float* Wv = (const float*)d_in[7];
  const float* bv = (const float*)d_in[8];
  const float* Wo = (const float*)d_in[9];
  const float* bo = (const float*)d_in[10];
  float* out = (float*)d_out;

  bf16* WqT = (bf16*)d_ws;
  bf16* WkT = WqT + (size_t)D_MODEL*D_MODEL;
  bf16* WvT = WkT + (size_t)D_MODEL*D_MODEL;
  bf16* WoT = WvT + (size_t)D_MODEL*D_MODEL;
  bf16* Xb  = WoT + (size_t)D_MODEL*D_MODEL;   // 32 MB staging, reused q->k->v
  bf16* Ql  = Xb  + (size_t)MROWS*D_MODEL;
  bf16* Kl  = Ql  + (size_t)MROWS*D_MODEL;     // K_lin^T [1024][16384]
  bf16* Vb  = Kl  + (size_t)MROWS*D_MODEL;     // V^T     [1024][16384]
  bf16* Vl  = Kl;                              // reuse: KT dead after kv_kernel
  bf16* KVb = Vb + (size_t)MROWS*D_MODEL;      // [64][144][64] bf16 hi/lo
  // kv partials overlay the dead Xb region (dead after the V-projection GEMM)
  float* KVp = (float*)Xb;                                   // 16 MB
  float* Ksp = KVp + (size_t)NBATCH*NHEADS*KV_SPLIT*DH*DH;   // 256 KB

  transpose4<<<dim3(32,32,4), dim3(32,32,1), 0, stream>>>(Wq,Wk,Wv,Wo, WqT,WkT,WvT,WoT);

  const int nconv4 = MROWS*D_MODEL/4;
  dim3 gb(512), gg(D_MODEL/256, MROWS/128);    // (4, 128) = 512 blocks = 2/CU

  cvt_bf16<<<nconv4/256, 256, 0, stream>>>(q, Xb);
  gemm_bias_act<1,0,bf16><<<gg, gb, 0, stream>>>(Xb, WqT, bq, Ql, MROWS, D_MODEL, D_MODEL);
  cvt_bf16<<<nconv4/256, 256, 0, stream>>>(k, Xb);
  gemm_bias_act<1,1,bf16><<<gg, gb, 0, stream>>>(Xb, WkT, bk, Kl, MROWS, D_MODEL, D_MODEL);
  cvt_bf16<<<nconv4/256, 256, 0, stream>>>(v, Xb);
  gemm_bias_act<0,1,bf16><<<gg, gb, 0, stream>>>(Xb, WvT, bv, Vb, MROWS, D_MODEL, D_MODEL);

  kv_kernel<<<dim3(NBATCH*NHEADS*KV_SPLIT), dim3(256), 0, stream>>>(Kl, Vb, KVp, Ksp);
  kv_reduce<<<dim3(4, NBATCH*NHEADS), dim3(256), 0, stream>>>(KVp, Ksp, KVb);
  vlin_kernel<<<dim3(SEQLEN/128, NBATCH*NHEADS), dim3(256), 0, stream>>>(Ql, KVb, Vl);

  gemm_bias_act<0,0,float><<<gg, gb, 0, stream>>>(Vl, WoT, bo, out, MROWS, D_MODEL, D_MODEL);
}

// Round 5
// 463.402 us; speedup vs baseline: 1.0268x; 1.0268x over previous
//
#include <hip/hip_runtime.h>
#include <hip/hip_bf16.h>
#include <stdint.h>

#define D_MODEL 1024
#define NHEADS  16
#define DH      64
#define NBATCH  4
#define SEQLEN  4096
#define MROWS   (NBATCH*SEQLEN)   // 16384
#define EPSV    1e-10f

typedef __hip_bfloat16 bf16;
typedef unsigned short ushort_t;
typedef __attribute__((ext_vector_type(8))) short short8;   // 8 bf16 (4 VGPRs)
typedef __attribute__((ext_vector_type(4))) float f32x4;

struct __align__(8) bf16x4s { bf16 a, b, c, d; };

__device__ __forceinline__ void async_copy16(void* lds, const void* g) {
  __builtin_amdgcn_global_load_lds(
      (const __attribute__((address_space(1))) unsigned int*)(uintptr_t)g,
      (__attribute__((address_space(3))) unsigned int*)(uintptr_t)lds,
      16, 0, 0);
}

// ---------------- f32 -> bf16 conversion (vectorized, exact grid) ----------------
__global__ __launch_bounds__(256)
void cvt_bf16(const float* __restrict__ s, bf16* __restrict__ d) {
  const int i = blockIdx.x * 256 + threadIdx.x;
  const f32x4 v = ((const f32x4*)s)[i];
  bf16x4s o;
  o.a = __float2bfloat16(v[0]);
  o.b = __float2bfloat16(v[1]);
  o.c = __float2bfloat16(v[2]);
  o.d = __float2bfloat16(v[3]);
  ((bf16x4s*)d)[i] = o;
}

// ---------------- weight transpose + cvt (W[K,N] f32 -> WT[N,K] bf16) ----------------
__global__ void transpose4(const float* __restrict__ s0, const float* __restrict__ s1,
                           const float* __restrict__ s2, const float* __restrict__ s3,
                           bf16* __restrict__ d0, bf16* __restrict__ d1,
                           bf16* __restrict__ d2, bf16* __restrict__ d3) {
  const float* s; bf16* d;
  switch (blockIdx.z) {
    case 0: s = s0; d = d0; break;
    case 1: s = s1; d = d1; break;
    case 2: s = s2; d = d2; break;
    default: s = s3; d = d3; break;
  }
  __shared__ float tile[32][33];
  int x = blockIdx.x*32 + threadIdx.x;
  int y = blockIdx.y*32 + threadIdx.y;
  tile[threadIdx.y][threadIdx.x] = s[(size_t)y*D_MODEL + x];
  __syncthreads();
  int xo = blockIdx.y*32 + threadIdx.x;
  int yo = blockIdx.x*32 + threadIdx.y;
  d[(size_t)yo*D_MODEL + xo] = __float2bfloat16(tile[threadIdx.x][threadIdx.y]);
}

// ---------------- GEMM: C = act(A[M,K] @ BT[N,K]^T + bias) ----------------
// Round-2 proven config: 128x256 tile, BK=32, 8 waves (2Mx4N, 64x64 each),
// double-buffered LDS, counted-vmcnt 2-phase schedule (T3/T4), XCD swizzle.
// TRANS=1: write output transposed as C_T[N][M] (r2 contiguous -> 8B stores).
__device__ __forceinline__ void storeC(float* p, float v) { *p = v; }
__device__ __forceinline__ void storeC(bf16*  p, float v) { *p = __float2bfloat16(v); }

template<int ACT, int TRANS, typename CT>
__global__ __launch_bounds__(512, 4)
void gemm_bias_act(const bf16* __restrict__ A, const bf16* __restrict__ BT,
                   const float* __restrict__ bias, CT* __restrict__ C,
                   int M, int N, int K) {
  __shared__ __align__(16) short Asm[2][128*32];
  __shared__ __align__(16) short Bsm[2][256*32];
  const int tid  = threadIdx.x;          // 0..511
  const int wave = tid >> 6;             // 0..7
  const int lane = tid & 63;

  // XCD-aware bijective swizzle of the flattened block id (nwg % 8 == 0)
  const int nbx = N >> 8;                            // N/256
  const int nwg = (M >> 7) * nbx;
  int fid = blockIdx.y * nbx + blockIdx.x;
  fid = (fid & 7) * (nwg >> 3) + (fid >> 3);
  const int m0 = (fid / nbx) * 128;
  const int n0 = (fid % nbx) * 256;

  const int wr = wave >> 2, wc = wave & 3;           // 2M x 4N wave grid
  const int srow = tid >> 2;                         // 0..127 staging row
  const int ldst = (tid & 3) * 8;                    // linear LDS slot (shorts)
  const int sgrp = ((tid & 3) ^ ((srow >> 1) & 3)) * 8;  // swizzled source col-group
  const int fr   = lane & 15;
  const int quad = lane >> 4;
  const int sslot = (quad ^ ((fr >> 1) & 3)) * 8;    // swizzled read slot

  f32x4 acc[4][4] = {};
  const int nk = K / 32;

  // prologue: stage tile 0 into buffer 0 (3 loads/thread: 1 A-row, 2 B-rows)
  async_copy16(&Asm[0][srow*32 + ldst], A + (size_t)(m0+srow)*K + sgrp);
  #pragma unroll
  for (int r = 0; r < 2; ++r) {
    const int row = r*128 + srow;
    async_copy16(&Bsm[0][row*32 + ldst], BT + (size_t)(n0+row)*K + sgrp);
  }

  int cur = 0;
  for (int t = 0; t < nk; ++t) {
    if (t + 1 < nk) {
      const int k0n = (t + 1) * 32;
      async_copy16(&Asm[cur^1][srow*32 + ldst], A + (size_t)(m0+srow)*K + k0n + sgrp);
      #pragma unroll
      for (int r = 0; r < 2; ++r) {
        const int row = r*128 + srow;
        async_copy16(&Bsm[cur^1][row*32 + ldst], BT + (size_t)(n0+row)*K + k0n + sgrp);
      }
      asm volatile("s_waitcnt vmcnt(3)" ::: "memory");  // tile t's 3 loads done
    } else {
      asm volatile("s_waitcnt vmcnt(0)" ::: "memory");  // last tile: full drain
    }
    asm volatile("s_barrier" ::: "memory");             // buf[cur] ready for all

    short8 afr[4], bfr[4];
    #pragma unroll
    for (int i = 0; i < 4; ++i)
      afr[i] = *(const short8*)&Asm[cur][(wr*64 + i*16 + fr)*32 + sslot];
    #pragma unroll
    for (int j = 0; j < 4; ++j)
      bfr[j] = *(const short8*)&Bsm[cur][(wc*64 + j*16 + fr)*32 + sslot];

    __builtin_amdgcn_s_setprio(1);
    #pragma unroll
    for (int i = 0; i < 4; ++i)
      #pragma unroll
      for (int j = 0; j < 4; ++j)
        acc[i][j] = __builtin_amdgcn_mfma_f32_16x16x32_bf16(afr[i], bfr[j], acc[i][j], 0, 0, 0);
    __builtin_amdgcn_s_setprio(0);

    asm volatile("s_barrier" ::: "memory");             // reads done before overwrite
    cur ^= 1;
  }

  // C/D layout: col(n)=lane&15, row(m)=quad*4+reg  [measured m89/m91]
  #pragma unroll
  for (int j = 0; j < 4; ++j) {
    const int gn = n0 + wc*64 + j*16 + fr;
    const float bv = bias[gn];
    #pragma unroll
    for (int i = 0; i < 4; ++i) {
      const int gm = m0 + wr*64 + i*16 + quad*4;
      if (TRANS) {
        float vv[4];
        #pragma unroll
        for (int r2 = 0; r2 < 4; ++r2) {
          float v = acc[i][j][r2] + bv;
          if (ACT) v = (v > 0.f) ? (v + 1.f) : __expf(v);
          vv[r2] = v;
        }
        bf16x4s o{__float2bfloat16(vv[0]), __float2bfloat16(vv[1]),
                  __float2bfloat16(vv[2]), __float2bfloat16(vv[3])};
        *(bf16x4s*)((bf16*)C + (size_t)gn*M + gm) = o;   // C_T[N][M], r2 contiguous
      } else {
        #pragma unroll
        for (int r2 = 0; r2 < 4; ++r2) {
          float v = acc[i][j][r2] + bv;
          if (ACT) v = (v > 0.f) ? (v + 1.f) : __expf(v);   // elu(x)+1
          storeC(&C[(size_t)(gm + r2)*N + gn], v);
        }
      }
    }
  }
}

// ---------------- KV + K_sum partials via MFMA (transposed inputs, LDS-staged) ----
// KT,VT are [1024][MROWS] bf16 (pre-transposed by the K/V projection GEMMs).
// Per block (nh, sp): stage 64x256-s strips of KT,VT into LDS via global_load_lds
// (rows s-contiguous -> coalesced 16B/lane; dest tid-linear per m104), group
// XOR-swizzle (g ^= row&7) on BOTH source and read side -> uniform bank spread.
// KV[m][d] += sum_s V[m][s]*K[d][s]; Ksum via ones-row MFMA (wave 0).
#define KV_SPLIT 16
__global__ __launch_bounds__(256)
void kv_kernel(const bf16* __restrict__ KT, const bf16* __restrict__ VT,
               float* __restrict__ KVp, float* __restrict__ Ksp) {
  const int b  = blockIdx.x;
  const int sp = b & (KV_SPLIT-1);
  const int nh = b >> 4;
  const int h = nh & (NHEADS-1), n = nh >> 4;
  const int tid = threadIdx.x;
  const int w = tid >> 6, lane = tid & 63;
  const int fr = lane & 15, quad = lane >> 4;

  __shared__ __align__(16) short Kt[64*256];   // 32 KB
  __shared__ __align__(16) short Vt[64*256];   // 32 KB

  const size_t cbase = (size_t)n*SEQLEN + sp*(SEQLEN/KV_SPLIT);
  const bf16* KTh = KT + (size_t)(h*DH)*MROWS + cbase;
  const bf16* VTh = VT + (size_t)(h*DH)*MROWS + cbase;

  // stage: each wave-load covers 2 rows x 32 groups of 16B (tid-linear dest)
  const int lr = lane >> 5;        // 0..1
  const int g  = lane & 31;        // 16B group within row
  #pragma unroll
  for (int i = 0; i < 8; ++i) {
    const int row = (i*4 + w)*2 + lr;
    const int sg = g ^ (row & 7);
    async_copy16(&Kt[row*256 + g*8], KTh + (size_t)row*MROWS + sg*8);
  }
  #pragma unroll
  for (int i = 0; i < 8; ++i) {
    const int row = (i*4 + w)*2 + lr;
    const int sg = g ^ (row & 7);
    async_copy16(&Vt[row*256 + g*8], VTh + (size_t)row*MROWS + sg*8);
  }
  __syncthreads();   // vmcnt(0)+lgkm+barrier: tiles resident

  f32x4 acc[4] = {};
  f32x4 ksacc[4] = {};
  const short8 ones8 = {0x3F80,0x3F80,0x3F80,0x3F80,0x3F80,0x3F80,0x3F80,0x3F80};
  const int arow = w*16 + fr;

  #pragma unroll
  for (int ks = 0; ks < 8; ++ks) {        // 8 x 32 = 256 s per block
    const int gq = ks*4 + quad;
    const short8 av = *(const short8*)&Vt[arow*256 + ((gq ^ (arow & 7)) << 3)];
    #pragma unroll
    for (int j = 0; j < 4; ++j) {
      const int brow = j*16 + fr;
      const short8 bk = *(const short8*)&Kt[brow*256 + ((gq ^ (brow & 7)) << 3)];
      acc[j] = __builtin_amdgcn_mfma_f32_16x16x32_bf16(av, bk, acc[j], 0, 0, 0);
      if (w == 0)
        ksacc[j] = __builtin_amdgcn_mfma_f32_16x16x32_bf16(ones8, bk, ksacc[j], 0, 0, 0);
    }
  }

  // KV partial: m = w*16 + quad*4 + r, col d = j*16 + fr
  float* outp = KVp + (size_t)b*4096;
  #pragma unroll
  for (int j = 0; j < 4; ++j)
    #pragma unroll
    for (int r = 0; r < 4; ++r)
      outp[(w*16 + quad*4 + r)*64 + j*16 + fr] = acc[j][r];

  if (tid < 16)   // wave 0, quad 0: every C-row of ones-MFMA equals Ksum_partial
    #pragma unroll
    for (int j = 0; j < 4; ++j)
      Ksp[b*64 + j*16 + tid] = ksacc[j][0];
}

// ---------------- reduce 16 partials -> KVb (bf16 hi/lo, vlin B-frag layout) ----
// KVb[nh][144][64]: rows 0-63 hi(KV[m][d]), 64-127 lo, 128/129 Ksum hi/lo,
// 130-143 zero pad (so vlin's j=8 fragment rows are defined).
__global__ __launch_bounds__(256)
void kv_reduce(const float* __restrict__ KVp, const float* __restrict__ Ksp,
               bf16* __restrict__ KVb) {
  const int c  = blockIdx.x;    // 0..3
  const int nh = blockIdx.y;    // 0..63
  const int tid = threadIdx.x;
  const int e = c*1024 + tid*4;
  const int m = e >> 6, d = e & 63;
  f32x4 s = {};
  #pragma unroll
  for (int sp = 0; sp < KV_SPLIT; ++sp)
    s += *(const f32x4*)(KVp + ((size_t)(nh*KV_SPLIT + sp))*4096 + e);

  bf16* base = KVb + (size_t)nh*(144*64);
  bf16 h0 = __float2bfloat16(s[0]), h1 = __float2bfloat16(s[1]);
  bf16 h2 = __float2bfloat16(s[2]), h3 = __float2bfloat16(s[3]);
  bf16x4s hi4{h0, h1, h2, h3};
  bf16x4s lo4{__float2bfloat16(s[0] - __bfloat162float(h0)),
              __float2bfloat16(s[1] - __bfloat162float(h1)),
              __float2bfloat16(s[2] - __bfloat162float(h2)),
              __float2bfloat16(s[3] - __bfloat162float(h3))};
  *(bf16x4s*)&base[m*64 + d]        = hi4;
  *(bf16x4s*)&base[(64 + m)*64 + d] = lo4;

  if (c == 0) {
    if (tid < 64) {
      float ks = 0.f;
      #pragma unroll
      for (int sp = 0; sp < KV_SPLIT; ++sp)
        ks += Ksp[(nh*KV_SPLIT + sp)*64 + tid];
      bf16 hh = __float2bfloat16(ks);
      base[128*64 + tid] = hh;
      base[129*64 + tid] = __float2bfloat16(ks - __bfloat162float(hh));
    }
    for (int i2 = tid; i2 < 14*64; i2 += 256)
      base[130*64 + i2] = __float2bfloat16(0.0f);
  }
}

// ---------------- V_lin = Z * (Q_lin . KV) — Q LDS-staged, KVb direct (L2-hot) ----
__global__ __launch_bounds__(256)
void vlin_kernel(const bf16* __restrict__ Ql, const bf16* __restrict__ KVb,
                 bf16* __restrict__ Vl) {
  const int lc = blockIdx.x;            // l-chunk of 128 rows (32 total)
  const int nh = blockIdx.y;            // n*NHEADS + h
  const int h = nh & (NHEADS-1), n = nh >> 4;
  const int tid = threadIdx.x, wave = tid >> 6, lane = tid & 63;
  const int fr = lane & 15, quad = lane >> 4;

  __shared__ __align__(16) short Qs[128*64];   // 16 KB

  // ---- stage Q tile [128 rows][64 d] via global_load_lds (coalesced) ----
  const int l0 = lc * 128;
  const size_t qbase = ((size_t)(n*SEQLEN) + l0)*D_MODEL + h*DH;
  const int lr8 = lane >> 3;            // 0..7: row within wave-load
  const int g8  = lane & 7;             // 16B group within row
  #pragma unroll
  for (int i = 0; i < 4; ++i) {
    const int row = (i*4 + wave)*8 + lr8;
    const int sg = g8 ^ (row & 7);
    async_copy16(&Qs[row*64 + g8*8], Ql + qbase + (size_t)row*D_MODEL + sg*8);
  }
  __syncthreads();

  // ---- A fragments from LDS (swizzled read) ----
  short8 afr[2][2];
  #pragma unroll
  for (int i = 0; i < 2; ++i)
    #pragma unroll
    for (int ks = 0; ks < 2; ++ks) {
      const int arow = wave*32 + i*16 + fr;
      afr[i][ks] = *(const short8*)&Qs[arow*64 + (((ks*4 + quad) ^ (fr & 7)) << 3)];
    }

  // ---- B fragments: direct from KVb (L2-resident, frag-ready layout) ----
  const bf16* bb = KVb + (size_t)nh*(144*64);
  f32x4 acc[2][9] = {};
  #pragma unroll
  for (int ks = 0; ks < 2; ++ks) {
    #pragma unroll
    for (int j = 0; j < 9; ++j) {
      const short8 bfr = *(const short8*)(bb + (j*16 + fr)*64 + ks*32 + quad*8);
      #pragma unroll
      for (int i = 0; i < 2; ++i)
        acc[i][j] = __builtin_amdgcn_mfma_f32_16x16x32_bf16(afr[i][ks], bfr, acc[i][j], 0, 0, 0);
    }
  }

  // ---- scale + store; Z via shfl broadcast (no extra LDS round-trip) ----
  #pragma unroll
  for (int i = 0; i < 2; ++i) {
    #pragma unroll
    for (int r2 = 0; r2 < 4; ++r2) {
      const float v = acc[i][8][r2];
      const float vp = v + __shfl_xor(v, 1, 64);          // P128 + P129 (valid at fr=0)
      const float z = 1.0f / (__shfl(vp, lane & 48, 64) + EPSV);  // bcast from quad's fr=0
      const int rloc = wave*32 + i*16 + quad*4 + r2;
      #pragma unroll
      for (int j = 0; j < 4; ++j) {
        const float num = acc[i][j][r2] + acc[i][4 + j][r2];
        Vl[qbase + (size_t)rloc*D_MODEL + j*16 + fr] = __float2bfloat16(num * z);
      }
    }
  }
}

// ---------------- launch ----------------
extern "C" void kernel_launch(void* const* d_in, const int* in_sizes, int n_in,
                              void* d_out, int out_size, void* d_ws, size_t ws_size,
                              hipStream_t stream) {
  const float* q  = (const float*)d_in[0];
  const float* k  = (const float*)d_in[1];
  const float* v  = (const float*)d_in[2];
  const float* Wq = (const float*)d_in[3];
  const float* bq = (const float*)d_in[4];
  const float* Wk = (const float*)d_in[5];
  const float* bk = (const float*)d_in[6];
  const float* Wv = (const float*)d_in[7];
  const float* bv = (const float*)d_in[8];
  const float* Wo = (const float*)d_in[9];
  const float* bo = (const float*)d_in[10];
  float* out = (float*)d_out;

  bf16* WqT = (bf16*)d_ws;
  bf16* WkT = WqT + (size_t)D_MODEL*D_MODEL;
  bf16* WvT = WkT + (size_t)D_MODEL*D_MODEL;
  bf16* WoT = WvT + (size_t)D_MODEL*D_MODEL;
  bf16* Xb  = WoT + (size_t)D_MODEL*D_MODEL;   // 32 MB staging, reused q->k->v
  bf16* Ql  = Xb  + (size_t)MROWS*D_MODEL;
  bf16* Kl  = Ql  + (size_t)MROWS*D_MODEL;     // K_lin^T [1024][16384]
  bf16* Vb  = Kl  + (size_t)MROWS*D_MODEL;     // V^T     [1024][16384]
  bf16* Vl  = Kl;                              // reuse: KT dead after kv_kernel
  bf16* KVb = Vb + (size_t)MROWS*D_MODEL;      // [64][144][64] bf16 hi/lo
  // kv partials overlay the dead Xb region (dead after the V-projection GEMM)
  float* KVp = (float*)Xb;                                   // 16 MB
  float* Ksp = KVp + (size_t)NBATCH*NHEADS*KV_SPLIT*DH*DH;   // 256 KB

  transpose4<<<dim3(32,32,4), dim3(32,32,1), 0, stream>>>(Wq,Wk,Wv,Wo, WqT,WkT,WvT,WoT);

  const int nconv4 = MROWS*D_MODEL/4;
  dim3 gb(512), gg(D_MODEL/256, MROWS/128);    // (4, 128) = 512 blocks = 2/CU

  cvt_bf16<<<nconv4/256, 256, 0, stream>>>(q, Xb);
  gemm_bias_act<1,0,bf16><<<gg, gb, 0, stream>>>(Xb, WqT, bq, Ql, MROWS, D_MODEL, D_MODEL);
  cvt_bf16<<<nconv4/256, 256, 0, stream>>>(k, Xb);
  gemm_bias_act<1,1,bf16><<<gg, gb, 0, stream>>>(Xb, WkT, bk, Kl, MROWS, D_MODEL, D_MODEL);
  cvt_bf16<<<nconv4/256, 256, 0, stream>>>(v, Xb);
  gemm_bias_act<0,1,bf16><<<gg, gb, 0, stream>>>(Xb, WvT, bv, Vb, MROWS, D_MODEL, D_MODEL);

  kv_kernel<<<dim3(NBATCH*NHEADS*KV_SPLIT), dim3(256), 0, stream>>>(Kl, Vb, KVp, Ksp);
  kv_reduce<<<dim3(4, NBATCH*NHEADS), dim3(256), 0, stream>>>(KVp, Ksp, KVb);
  vlin_kernel<<<dim3(SEQLEN/128, NBATCH*NHEADS), dim3(256), 0, stream>>>(Ql, KVb, Vl);

  gemm_bias_act<0,0,float><<<gg, gb, 0, stream>>>(Vl, WoT, bo, out, MROWS, D_MODEL, D_MODEL);
}